// Round 1
// baseline (257.935 us; speedup 1.0000x reference)
//
#include <hip/hip_runtime.h>

// Product quantizer: N=16384 rows, D=1024 dims, M=64 subspaces, K=256 codes, d=16.
// Main pass: f32 score = x·c - 0.5*||c||^2, argmax per (n,m), track top-2 gap.
// Ambiguous cases (gap < MARGIN) re-decided in f64 by a refine kernel.

#define NROWS 16384
#define DIM   1024
#define MSUB  64
#define KCODE 256
#define DSUB  16

static constexpr float MARGIN = 1e-3f;

__global__ __launch_bounds__(256) void pq_main_kernel(
    const float* __restrict__ embeds,
    const float* __restrict__ codebooks,
    float* __restrict__ out,
    unsigned int* __restrict__ flag_cnt,
    unsigned int* __restrict__ flag_list,
    unsigned int flag_cap)
{
    __shared__ float cb[KCODE * DSUB];  // codebook[m], [k][d]
    __shared__ float hh[KCODE];         // 0.5*||c_k||^2

    const int bid = blockIdx.x;
    const int m = bid & 63;        // subspace
    const int g = bid >> 6;        // row group (1024 rows)
    const int tid = threadIdx.x;

    // Stage codebook[m]: 4096 floats, 256 threads x 4 float4 each. Coalesced.
    {
        const float4* src = (const float4*)(codebooks + (size_t)m * (KCODE * DSUB));
        float4* dst = (float4*)cb;
        #pragma unroll
        for (int i = 0; i < 4; ++i) dst[tid + 256 * i] = src[tid + 256 * i];
    }
    __syncthreads();

    // h[k] = 0.5 * sum c^2  (one k per thread)
    {
        const float* c = cb + tid * DSUB;
        float s = 0.f;
        #pragma unroll
        for (int dd = 0; dd < DSUB; ++dd) s = fmaf(c[dd], c[dd], s);
        hh[tid] = 0.5f * s;
    }
    __syncthreads();

    const int w = tid >> 6;        // wave in block
    const int l = tid & 63;        // lane
    const int n0 = g * 1024 + w * 256 + l;   // rows n0 + 64*r, r=0..3

    // Load x slices: 4 rows x 16 floats into registers.
    float x[4][DSUB];
    #pragma unroll
    for (int r = 0; r < 4; ++r) {
        const float4* xs = (const float4*)(embeds + (size_t)(n0 + 64 * r) * DIM + m * DSUB);
        #pragma unroll
        for (int q = 0; q < 4; ++q) {
            float4 v = xs[q];
            x[r][4*q+0] = v.x; x[r][4*q+1] = v.y;
            x[r][4*q+2] = v.z; x[r][4*q+3] = v.w;
        }
    }

    float best[4], second[4];
    int   idx[4];
    #pragma unroll
    for (int r = 0; r < 4; ++r) { best[r] = -3.4e38f; second[r] = -3.4e38f; idx[r] = 0; }

    for (int k = 0; k < KCODE; ++k) {
        const float4* cv = (const float4*)(cb + k * DSUB);
        float4 c0 = cv[0], c1 = cv[1], c2 = cv[2], c3 = cv[3];
        float nh = -hh[k];
        #pragma unroll
        for (int r = 0; r < 4; ++r) {
            float s;
            s = fmaf(x[r][0],  c0.x, nh);
            s = fmaf(x[r][1],  c0.y, s);
            s = fmaf(x[r][2],  c0.z, s);
            s = fmaf(x[r][3],  c0.w, s);
            s = fmaf(x[r][4],  c1.x, s);
            s = fmaf(x[r][5],  c1.y, s);
            s = fmaf(x[r][6],  c1.z, s);
            s = fmaf(x[r][7],  c1.w, s);
            s = fmaf(x[r][8],  c2.x, s);
            s = fmaf(x[r][9],  c2.y, s);
            s = fmaf(x[r][10], c2.z, s);
            s = fmaf(x[r][11], c2.w, s);
            s = fmaf(x[r][12], c3.x, s);
            s = fmaf(x[r][13], c3.y, s);
            s = fmaf(x[r][14], c3.z, s);
            s = fmaf(x[r][15], c3.w, s);
            bool gt = s > best[r];
            idx[r]   = gt ? k : idx[r];
            float t  = fminf(s, best[r]);     // loser of this round
            second[r]= fmaxf(second[r], t);
            best[r]  = fmaxf(best[r], s);
        }
    }

    // Epilogue: write chosen codewords; flag ambiguous decisions.
    #pragma unroll
    for (int r = 0; r < 4; ++r) {
        const int n = n0 + 64 * r;
        const float4* c = (const float4*)(cb + idx[r] * DSUB);
        float4* o = (float4*)(out + (size_t)n * DIM + m * DSUB);
        o[0] = c[0]; o[1] = c[1]; o[2] = c[2]; o[3] = c[3];
        if (best[r] - second[r] < MARGIN) {
            unsigned int p = atomicAdd(flag_cnt, 1u);
            if (p < flag_cap) flag_list[p] = (unsigned int)(n * 64 + m);
        }
    }
}

__global__ __launch_bounds__(256) void pq_refine_kernel(
    const float* __restrict__ embeds,
    const float* __restrict__ codebooks,
    float* __restrict__ out,
    const unsigned int* __restrict__ flag_cnt,
    const unsigned int* __restrict__ flag_list,
    unsigned int flag_cap)
{
    unsigned int cnt = *flag_cnt;
    if (cnt > flag_cap) cnt = flag_cap;
    const unsigned int stride = gridDim.x * blockDim.x;
    for (unsigned int i = blockIdx.x * blockDim.x + threadIdx.x; i < cnt; i += stride) {
        unsigned int e = flag_list[i];
        int n = (int)(e >> 6);
        int m = (int)(e & 63u);
        const float* xp = embeds + (size_t)n * DIM + m * DSUB;
        double x[DSUB];
        #pragma unroll
        for (int dd = 0; dd < DSUB; ++dd) x[dd] = (double)xp[dd];
        const float* cbm = codebooks + (size_t)m * (KCODE * DSUB);
        double bestd = 1e300;
        int bi = 0;
        for (int k = 0; k < KCODE; ++k) {
            const float* c = cbm + k * DSUB;
            double s = 0.0;
            #pragma unroll
            for (int dd = 0; dd < DSUB; ++dd) {
                double diff = x[dd] - (double)c[dd];
                s = fma(diff, diff, s);
            }
            if (s < bestd) { bestd = s; bi = k; }  // strict < keeps first index
        }
        const float* c = cbm + bi * DSUB;
        float* o = out + (size_t)n * DIM + m * DSUB;
        #pragma unroll
        for (int dd = 0; dd < DSUB; ++dd) o[dd] = c[dd];
    }
}

extern "C" void kernel_launch(void* const* d_in, const int* in_sizes, int n_in,
                              void* d_out, int out_size, void* d_ws, size_t ws_size,
                              hipStream_t stream)
{
    const float* embeds    = (const float*)d_in[0];
    const float* codebooks = (const float*)d_in[1];
    float* out = (float*)d_out;

    unsigned int* flag_cnt  = (unsigned int*)d_ws;
    unsigned int* flag_list = (unsigned int*)d_ws + 4;  // 16B offset
    unsigned int flag_cap = 0;
    if (ws_size >= 32) {
        size_t cap = (ws_size - 16) / sizeof(unsigned int);
        flag_cap = (cap > 0x7FFFFFFFull) ? 0x7FFFFFFFu : (unsigned int)cap;
    }

    hipMemsetAsync(d_ws, 0, 16, stream);

    // 64 m-values x 16 row-groups of 1024 rows
    pq_main_kernel<<<dim3(1024), dim3(256), 0, stream>>>(
        embeds, codebooks, out, flag_cnt, flag_list, flag_cap);

    pq_refine_kernel<<<dim3(256), dim3(256), 0, stream>>>(
        embeds, codebooks, out, flag_cnt, flag_list, flag_cap);
}